// Round 2
// baseline (207.590 us; speedup 1.0000x reference)
//
#include <hip/hip_runtime.h>
#include <hip/hip_bf16.h>
#include <stdint.h>

#define T_TOKENS 8192
#define D_DIM    1024
#define NE       10
#define NT       8
#define SEG      2048   // padded per-expert list capacity (actual ~1638+-40)

typedef unsigned short u16;
typedef __attribute__((ext_vector_type(8))) __bf16 bf16x8;
typedef __attribute__((ext_vector_type(4))) float  f32x4;
typedef __attribute__((ext_vector_type(8))) unsigned short u16x8;
typedef __attribute__((ext_vector_type(4))) unsigned short u16x4;

static __device__ __forceinline__ u16 f32_to_bf16(float f) {
  union { float f; uint32_t u; } v; v.f = f;
  uint32_t u = v.u;
  return (u16)((u + 0x7fffu + ((u >> 16) & 1u)) >> 16);
}

// async 16B global->LDS DMA; LDS dest = wave-uniform base + lane*16 [m97/m104]
static __device__ __forceinline__ void async_load16(const u16* g, u16* l) {
  __builtin_amdgcn_global_load_lds(
      (const __attribute__((address_space(1))) void*)(const void*)g,
      (__attribute__((address_space(3))) void*)(void*)l, 16, 0, 0);
}

// ---------------------------------------------------------------------------
// Kernel 1: prep = gate + weight-transpose + out-zeroing fused (all
// independent, all BW-bound; fusing removes launch gaps).
//   blockIdx.x <  512 : gate role (16 tokens/block)
//   512..2559         : transpose role (64x64 fp32->bf16 tile of W)
//   2560..2815        : zero role (each clears 128KB of out for the
//                       R7 atomic-accumulate epilogue in moe_gemm)
// Gate: fp32 logits -> softmax -> top-2 (strict > scan = lax.top_k
// lower-index tie-break) -> normalized true weights; bf16 x; combined
// per-expert token lists + per-(expert,pos) combine weight wList.
// (revIdx/revW reverse map deleted in R7 — combine kernel is gone.)
// ---------------------------------------------------------------------------
union PrepShared {
  struct { float gws[NE * D_DIM]; float gbs[NE]; int se[32]; float swt[32]; } g;
  struct { float tile[64][65]; } t;
};

__global__ __launch_bounds__(256) void prep_kernel(
    const float* __restrict__ x, const float* __restrict__ gw,
    const float* __restrict__ gb, const float* __restrict__ W,
    u16* __restrict__ xb, u16* __restrict__ wT,
    int* __restrict__ cnt, int* __restrict__ tokList,
    float* __restrict__ wList, float* __restrict__ out) {
  __shared__ PrepShared sh;
  int tid = threadIdx.x;

  if (blockIdx.x >= 2560) {
    // ---- zero role: clear out[8192][1024] fp32 (32MB / 256 blocks) ----
    int zr = blockIdx.x - 2560;
    f32x4* o4 = (f32x4*)out + (size_t)zr * 8192;
    f32x4 z = {0.f, 0.f, 0.f, 0.f};
    for (int i = tid; i < 8192; i += 256) o4[i] = z;
    return;
  }
  if (blockIdx.x >= 512) {
    // ---- transpose role: W [e][d][j] fp32 -> wT [e][j][d] bf16 ----
    int tb = blockIdx.x - 512;
    int e  = tb >> 8;
    int rem = tb & 255;
    int k0 = (rem >> 4) * 64;
    int n0 = (rem & 15) * 64;
    int c  = tid & 63;
    int r0 = tid >> 6;
    const float* We = W + ((size_t)e << 20);
#pragma unroll
    for (int rr = 0; rr < 16; ++rr) {
      int r = rr * 4 + r0;
      sh.t.tile[c][r] = We[(size_t)(k0 + r) * 1024 + n0 + c];
    }
    __syncthreads();
    u16* wTe = wT + ((size_t)e << 20);
#pragma unroll
    for (int rr = 0; rr < 16; ++rr) {
      int n = rr * 4 + r0;
      wTe[(size_t)(n0 + n) * 1024 + k0 + c] = f32_to_bf16(sh.t.tile[n][c]);
    }
    return;
  }

  // ---- gate role ----
  {
    const f32x4* g4 = (const f32x4*)gw;
    f32x4* s4 = (f32x4*)sh.g.gws;
    for (int i = tid; i < NE * D_DIM / 4; i += 256) s4[i] = g4[i];
  }
  if (tid < NE) sh.g.gbs[tid] = gb[tid];
  __syncthreads();
  int lane = tid & 63;
  int wv   = tid >> 6;
  const f32x4* gws4 = (const f32x4*)sh.g.gws;
  for (int it = 0; it < 4; ++it) {
    int slot = wv * 4 + it;
    int t = blockIdx.x * 16 + slot;
    const f32x4* xr4 = (const f32x4*)(x + (size_t)t * D_DIM);
    f32x4 xv[4];
#pragma unroll
    for (int jj = 0; jj < 4; ++jj) xv[jj] = xr4[lane + 64 * jj];
    u16x4* xbr = (u16x4*)(xb + (size_t)t * D_DIM);
#pragma unroll
    for (int jj = 0; jj < 4; ++jj) {
      u16x4 pk;
#pragma unroll
      for (int k = 0; k < 4; ++k) pk[k] = f32_to_bf16(xv[jj][k]);
      xbr[lane + 64 * jj] = pk;
    }
    float logit[NE];
#pragma unroll
    for (int e = 0; e < NE; ++e) {
      float a = 0.f;
#pragma unroll
      for (int jj = 0; jj < 4; ++jj) {
        f32x4 gv = gws4[e * 256 + lane + 64 * jj];
#pragma unroll
        for (int k = 0; k < 4; ++k) a = fmaf(xv[jj][k], gv[k], a);
      }
#pragma unroll
      for (int off = 32; off >= 1; off >>= 1) a += __shfl_xor(a, off);
      logit[e] = a + sh.g.gbs[e];
    }
    float mx = logit[0];
#pragma unroll
    for (int e = 1; e < NE; ++e) mx = fmaxf(mx, logit[e]);
    float p[NE]; float s = 0.f;
#pragma unroll
    for (int e = 0; e < NE; ++e) { p[e] = expf(logit[e] - mx); s += p[e]; }
    int e0 = 0; float b0 = p[0];
#pragma unroll
    for (int e = 1; e < NE; ++e) if (p[e] > b0) { b0 = p[e]; e0 = e; }
    int e1 = -1; float b1 = -1.f;
#pragma unroll
    for (int e = 0; e < NE; ++e) if (e != e0 && p[e] > b1) { b1 = p[e]; e1 = e; }
    float w0 = b0 / s, w1 = b1 / s;
    float tw0 = (e0 < NT) ? w0 : 0.f;
    float tw1 = (e1 < NT) ? w1 : 0.f;
    float denom = tw0 + tw1;
    float nw0 = 0.f, nw1 = 0.f;
    if (denom > 0.f) { nw0 = tw0 / denom; nw1 = tw1 / denom; }
    if (lane == 0) {
      sh.g.se[slot * 2]     = (e0 < NT) ? e0 : -1;  sh.g.swt[slot * 2]     = nw0;
      sh.g.se[slot * 2 + 1] = (e1 < NT) ? e1 : -1;  sh.g.swt[slot * 2 + 1] = nw1;
    }
  }
  __syncthreads();
  // compaction: thread e<8 scans 32 (token,slot) entries; one padded atomic.
  if (tid < NT) {
    int e = tid, cc = 0;
    for (int i = 0; i < 32; ++i) cc += (sh.g.se[i] == e);
    if (cc > 0) {
      int base = atomicAdd(&cnt[e * 32], cc);
      int j = 0;
      for (int i = 0; i < 32; ++i) {
        if (sh.g.se[i] == e) {
          int tt  = blockIdx.x * 16 + (i >> 1);
          int pos = base + j;
          tokList[e * SEG + pos] = tt;
          wList[e * SEG + pos]   = sh.g.swt[i];
          ++j;
        }
      }
    }
  }
}

// ---------------------------------------------------------------------------
// Kernel 2: per-expert gathered GEMM + fused combine. grid x=expert
// (XCD-affine). 128x128 tile, BK=32, 4 waves x 4x4 mfma_f32_16x16x32_bf16.
// R7: schedule reverted to the proven R5 form (barrier / issue kt+2 /
// vmcnt(8) / barrier — R6's wait-before-issue variant measured −5%: it
// shortened the DMA issue-ahead distance). Kept from R6: the 8-row XOR
// swizzle (kcd = kcp^((rl>>1)&3)): SQ_LDS_BANK_CONFLICT 3.47M -> 0
// (neutral on time here — 2-phase critical path hides LDS reads — but
// strictly free and required when the stage stall is later amortized).
// R7 epilogue: combine fused — each valid row ml atomically accumulates
// w * (acc + bias) in fp32 directly into out[token]; per out element <=2
// contributions (one per selected expert), atomics device-scope [m20],
// fp32 accumulate (more accurate than the old bf16 ybuf roundtrip).
// Rows gm>=c carry wS=0 and are skipped.
// ---------------------------------------------------------------------------
__global__ __launch_bounds__(256) void moe_gemm(
    const u16* __restrict__ xb, const u16* __restrict__ wT,
    const int* __restrict__ cnt, const int* __restrict__ tokList,
    const float* __restrict__ wList, const float* __restrict__ eb,
    float* __restrict__ out) {
  int e  = blockIdx.x;
  int c  = cnt[e * 32];
  int m0 = blockIdx.z * 128;
  if (m0 >= c) return;
  int n0 = blockIdx.y * 128;
  __shared__ __align__(16) u16 As[3][128 * 32];
  __shared__ __align__(16) u16 Bs[3][128 * 32];
  __shared__ int   tokS[128];
  __shared__ float wS[128];
  int tid = threadIdx.x;
  if (tid < 128) {
    int gm = m0 + tid;
    int valid = gm < c;
    tokS[tid] = valid ? tokList[e * SEG + gm] : tokList[e * SEG];
    wS[tid]   = valid ? wList[e * SEG + gm] : 0.f;
  }
  __syncthreads();
  int lane = tid & 63;
  int wv   = tid >> 6;
  // staging: wave wv covers rows [wv*32, wv*32+32); lane -> (row, chunk)
  int rl  = lane >> 2;             // 0..15
  int kcp = lane & 3;              // physical chunk slot
  int kcd = kcp ^ ((rl >> 1) & 3); // data chunk fetched (8-row XOR swizzle)
  int rowL0 = wv * 32 + rl, rowL1 = rowL0 + 16;
  const u16* gA0 = xb + (size_t)tokS[rowL0] * 1024 + kcd * 8;
  const u16* gA1 = xb + (size_t)tokS[rowL1] * 1024 + kcd * 8;
  const u16* wTe = wT + ((size_t)e << 20);
  const u16* gB0 = wTe + (size_t)(n0 + rowL0) * 1024 + kcd * 8;
  const u16* gB1 = wTe + (size_t)(n0 + rowL1) * 1024 + kcd * 8;
  int ldsA0 = (wv * 32) * 32, ldsA1 = (wv * 32 + 16) * 32;

  int wm = wv >> 1, wn = wv & 1;
  int lrow = lane & 15;
  int q    = lane >> 4;
  int sw   = (q ^ ((lrow >> 1) & 3)) * 8;   // matches 8-row write swizzle
  f32x4 acc[4][4];
#pragma unroll
  for (int i = 0; i < 4; ++i)
#pragma unroll
    for (int j = 0; j < 4; ++j) acc[i][j] = (f32x4){0.f, 0.f, 0.f, 0.f};

  // prologue: tiles 0,1 -> slots 0,1 (8 loads in flight)
#pragma unroll
  for (int p = 0; p < 2; ++p) {
    int ko = p * 32;
    async_load16(gA0 + ko, As[p] + ldsA0);
    async_load16(gA1 + ko, As[p] + ldsA1);
    async_load16(gB0 + ko, Bs[p] + ldsA0);
    async_load16(gB1 + ko, Bs[p] + ldsA1);
  }

  int cur = 0;                       // slot of tile kt (kt % 3)
  for (int kt = 0; kt < 32; ++kt) {
    // A: all waves done READING slot (kt-1)%3 == slot (kt+2)%3 (iter kt-1's
    // compute consumed it; lgkmcnt-before-MFMA makes those reads complete).
    asm volatile("s_barrier" ::: "memory");
    if (kt < 30) {
      int st = cur - 1; if (st < 0) st += 3;   // (kt+2) % 3
      int ko = (kt + 2) * 32;
      async_load16(gA0 + ko, As[st] + ldsA0);
      async_load16(gA1 + ko, As[st] + ldsA1);
      async_load16(gB0 + ko, Bs[st] + ldsA0);
      async_load16(gB1 + ko, Bs[st] + ldsA1);
      // 12 outstanding (tiles kt,kt+1,kt+2); wait tile kt's 4 only
      asm volatile("s_waitcnt vmcnt(8)" ::: "memory");
    } else if (kt == 30) {
      asm volatile("s_waitcnt vmcnt(4)" ::: "memory");
    } else {
      asm volatile("s_waitcnt vmcnt(0)" ::: "memory");
    }
    // B: every wave's tile-kt DMA has landed in LDS
    asm volatile("s_barrier" ::: "memory");
    bf16x8 af[4], bfr[4];
#pragma unroll
    for (int mt = 0; mt < 4; ++mt)
      af[mt] = *(const bf16x8*)(As[cur] + (wm * 64 + mt * 16 + lrow) * 32 + sw);
#pragma unroll
    for (int nt = 0; nt < 4; ++nt)
      bfr[nt] = *(const bf16x8*)(Bs[cur] + (wn * 64 + nt * 16 + lrow) * 32 + sw);
#pragma unroll
    for (int mt = 0; mt < 4; ++mt)
#pragma unroll
      for (int nt = 0; nt < 4; ++nt)
        acc[mt][nt] = __builtin_amdgcn_mfma_f32_16x16x32_bf16(
            af[mt], bfr[nt], acc[mt][nt], 0, 0, 0);
    ++cur; if (cur == 3) cur = 0;
  }
  // epilogue: C/D layout col=lane&15, row=(lane>>4)*4+reg [m89]
  // fused combine: out[tok][col] += w * (acc + bias), fp32 atomics.
  int rq = lane >> 4;
  float bias[4];
#pragma unroll
  for (int nt = 0; nt < 4; ++nt)
    bias[nt] = eb[e * 1024 + n0 + wn * 64 + nt * 16 + lrow];
#pragma unroll
  for (int mt = 0; mt < 4; ++mt) {
#pragma unroll
    for (int r = 0; r < 4; ++r) {
      int ml = wm * 64 + mt * 16 + rq * 4 + r;
      float w = wS[ml];
      if (w != 0.f) {
        float* orow = out + (size_t)tokS[ml] * 1024 + n0 + wn * 64 + lrow;
#pragma unroll
        for (int nt = 0; nt < 4; ++nt)
          atomicAdd(&orow[nt * 16], w * (acc[mt][nt][r] + bias[nt]));
      }
    }
  }
}

// ---------------------------------------------------------------------------
// Workspace layout (bytes), total ~32.2 MiB (ybuf/revIdx/revW deleted):
//   [0, 4096)        : int cnt[8*32] (one counter per 128B line)
//   [4096, +64K)     : tokList  8*2048 int (combined per-expert lists)
//   [+64K)           : wList    8*2048 float (combine weight per entry)
//   [+64K pad)       : (hole, keeps xb offset stable)
//   [200704, +16M)   : xb   bf16 [8192][1024]
//   [+16M)           : wT   bf16 [8][1024][1024]
// ---------------------------------------------------------------------------
extern "C" void kernel_launch(void* const* d_in, const int* in_sizes, int n_in,
                              void* d_out, int out_size, void* d_ws, size_t ws_size,
                              hipStream_t stream) {
  const float* x  = (const float*)d_in[0];
  const float* gw = (const float*)d_in[1];
  const float* gb = (const float*)d_in[2];
  const float* ew = (const float*)d_in[3];
  const float* eb = (const float*)d_in[4];
  float* out = (float*)d_out;
  char* ws = (char*)d_ws;
  int*   cnt     = (int*)ws;
  int*   tokList = (int*)(ws + 4096);
  float* wList   = (float*)(ws + 4096 + 65536);
  u16*   xb      = (u16*)(ws + 200704);
  u16*   wT      = (u16*)(ws + 200704 + 16777216);

  hipMemsetAsync(cnt, 0, 4096, stream);
  prep_kernel<<<2816, 256, 0, stream>>>(x, gw, gb, ew, xb, wT, cnt, tokList,
                                        wList, out);
  moe_gemm<<<dim3(8, 8, 16), 256, 0, stream>>>(xb, wT, cnt, tokList, wList,
                                               eb, out);
}

// Round 4
// 181.419 us; speedup vs baseline: 1.1443x; 1.1443x over previous
//
#include <hip/hip_runtime.h>
#include <hip/hip_bf16.h>
#include <stdint.h>

#define T_TOKENS 8192
#define D_DIM    1024
#define NE       10
#define NT       8
#define SEG      2048   // padded per-expert list capacity (actual ~1638+-40)

typedef unsigned short u16;
typedef __attribute__((ext_vector_type(8))) __bf16 bf16x8;
typedef __attribute__((ext_vector_type(4))) float  f32x4;
typedef __attribute__((ext_vector_type(8))) unsigned short u16x8;
typedef __attribute__((ext_vector_type(4))) unsigned short u16x4;

static __device__ __forceinline__ u16 f32_to_bf16(float f) {
  union { float f; uint32_t u; } v; v.f = f;
  uint32_t u = v.u;
  return (u16)((u + 0x7fffu + ((u >> 16) & 1u)) >> 16);
}
static __device__ __forceinline__ float bf16_to_f32(u16 u) {
  union { uint32_t u; float f; } v; v.u = ((uint32_t)u) << 16; return v.f;
}

// async 16B global->LDS DMA; LDS dest = wave-uniform base + lane*16 [m97/m104]
static __device__ __forceinline__ void async_load16(const u16* g, u16* l) {
  __builtin_amdgcn_global_load_lds(
      (const __attribute__((address_space(1))) void*)(const void*)g,
      (__attribute__((address_space(3))) void*)(void*)l, 16, 0, 0);
}

// ---------------------------------------------------------------------------
// Kernel 1: prep = gate + weight-transpose fused (independent, BW-bound).
//   blockIdx.x <  512 : gate role (16 tokens/block)
//   512..2559         : transpose role (64x64 fp32->bf16 tile of W)
// R8: transpose role vectorized (f32x4 loads, u16x4 stores; was 16 scalar
// f32 loads + 16 scalar bf16 stores per thread). LDS pad 65->68 floats so
// f32x4 row reads stay 16B-aligned (68*4 = 272 ≡ 0 mod 16).
// Gate: fp32 logits -> softmax -> top-2 (strict > scan = lax.top_k
// lower-index tie-break) -> normalized true weights; bf16 x; combined
// per-expert token lists; reverse index+weight per (token,slot) for combine.
// ---------------------------------------------------------------------------
union PrepShared {
  struct { float gws[NE * D_DIM]; float gbs[NE]; int se[32]; float swt[32]; } g;
  struct { float tile[64][68]; } t;
};

__global__ __launch_bounds__(256) void prep_kernel(
    const float* __restrict__ x, const float* __restrict__ gw,
    const float* __restrict__ gb, const float* __restrict__ W,
    u16* __restrict__ xb, u16* __restrict__ wT,
    int* __restrict__ cnt, int* __restrict__ tokList,
    int* __restrict__ revIdx, float* __restrict__ revW) {
  __shared__ PrepShared sh;
  int tid = threadIdx.x;

  if (blockIdx.x >= 512) {
    // ---- transpose role: W [e][d][j] fp32 -> wT [e][j][d] bf16 ----
    int tb = blockIdx.x - 512;
    int e  = tb >> 8;
    int rem = tb & 255;
    int k0 = (rem >> 4) * 64;
    int n0 = (rem & 15) * 64;
    int cr = tid & 15;            // col-chunk (load) / k-chunk (store)
    int r0 = tid >> 4;            // 0..15
    const float* We = W + ((size_t)e << 20);
#pragma unroll
    for (int pass = 0; pass < 4; ++pass) {
      int r = pass * 16 + r0;     // k-row within tile
      f32x4 v = *(const f32x4*)&We[(size_t)(k0 + r) * 1024 + n0 + cr * 4];
#pragma unroll
      for (int j = 0; j < 4; ++j) sh.t.tile[cr * 4 + j][r] = v[j];
    }
    __syncthreads();
    u16* wTe = wT + ((size_t)e << 20);
#pragma unroll
    for (int pass = 0; pass < 4; ++pass) {
      int n = pass * 16 + r0;     // output row (n-dim)
      f32x4 tv = *(const f32x4*)&sh.t.tile[n][cr * 4];
      u16x4 pk;
#pragma unroll
      for (int j = 0; j < 4; ++j) pk[j] = f32_to_bf16(tv[j]);
      *(u16x4*)&wTe[(size_t)(n0 + n) * 1024 + k0 + cr * 4] = pk;
    }
    return;
  }

  // ---- gate role ----
  {
    const f32x4* g4 = (const f32x4*)gw;
    f32x4* s4 = (f32x4*)sh.g.gws;
    for (int i = tid; i < NE * D_DIM / 4; i += 256) s4[i] = g4[i];
  }
  if (tid < NE) sh.g.gbs[tid] = gb[tid];
  __syncthreads();
  int lane = tid & 63;
  int wv   = tid >> 6;
  const f32x4* gws4 = (const f32x4*)sh.g.gws;
  for (int it = 0; it < 4; ++it) {
    int slot = wv * 4 + it;
    int t = blockIdx.x * 16 + slot;
    const f32x4* xr4 = (const f32x4*)(x + (size_t)t * D_DIM);
    f32x4 xv[4];
#pragma unroll
    for (int jj = 0; jj < 4; ++jj) xv[jj] = xr4[lane + 64 * jj];
    u16x4* xbr = (u16x4*)(xb + (size_t)t * D_DIM);
#pragma unroll
    for (int jj = 0; jj < 4; ++jj) {
      u16x4 pk;
#pragma unroll
      for (int k = 0; k < 4; ++k) pk[k] = f32_to_bf16(xv[jj][k]);
      xbr[lane + 64 * jj] = pk;
    }
    float logit[NE];
#pragma unroll
    for (int e = 0; e < NE; ++e) {
      float a = 0.f;
#pragma unroll
      for (int jj = 0; jj < 4; ++jj) {
        f32x4 gv = gws4[e * 256 + lane + 64 * jj];
#pragma unroll
        for (int k = 0; k < 4; ++k) a = fmaf(xv[jj][k], gv[k], a);
      }
#pragma unroll
      for (int off = 32; off >= 1; off >>= 1) a += __shfl_xor(a, off);
      logit[e] = a + sh.g.gbs[e];
    }
    float mx = logit[0];
#pragma unroll
    for (int e = 1; e < NE; ++e) mx = fmaxf(mx, logit[e]);
    float p[NE]; float s = 0.f;
#pragma unroll
    for (int e = 0; e < NE; ++e) { p[e] = expf(logit[e] - mx); s += p[e]; }
    int e0 = 0; float b0 = p[0];
#pragma unroll
    for (int e = 1; e < NE; ++e) if (p[e] > b0) { b0 = p[e]; e0 = e; }
    int e1 = -1; float b1 = -1.f;
#pragma unroll
    for (int e = 0; e < NE; ++e) if (e != e0 && p[e] > b1) { b1 = p[e]; e1 = e; }
    float w0 = b0 / s, w1 = b1 / s;
    float tw0 = (e0 < NT) ? w0 : 0.f;
    float tw1 = (e1 < NT) ? w1 : 0.f;
    float denom = tw0 + tw1;
    float nw0 = 0.f, nw1 = 0.f;
    if (denom > 0.f) { nw0 = tw0 / denom; nw1 = tw1 / denom; }
    if (lane == 0) {
      sh.g.se[slot * 2]     = (e0 < NT) ? e0 : -1;  sh.g.swt[slot * 2]     = nw0;
      sh.g.se[slot * 2 + 1] = (e1 < NT) ? e1 : -1;  sh.g.swt[slot * 2 + 1] = nw1;
      if (e0 >= NT) { revIdx[t * 2]     = -1; revW[t * 2]     = 0.f; }
      if (e1 >= NT) { revIdx[t * 2 + 1] = -1; revW[t * 2 + 1] = 0.f; }
    }
  }
  __syncthreads();
  // compaction: thread e<8 scans 32 (token,slot) entries; one padded atomic.
  if (tid < NT) {
    int e = tid, c = 0;
    for (int i = 0; i < 32; ++i) c += (sh.g.se[i] == e);
    if (c > 0) {
      int base = atomicAdd(&cnt[e * 32], c);
      int j = 0;
      for (int i = 0; i < 32; ++i) {
        if (sh.g.se[i] == e) {
          int tt  = blockIdx.x * 16 + (i >> 1);
          int pos = base + j;
          tokList[e * SEG + pos]   = tt;
          revIdx[tt * 2 + (i & 1)] = e * SEG + pos;
          revW[tt * 2 + (i & 1)]   = sh.g.swt[i];
          ++j;
        }
      }
    }
  }
}

// ---------------------------------------------------------------------------
// Kernel 2: per-expert gathered GEMM. grid x=expert (XCD-affine: expert e's
// blocks -> XCD e; 2MB B + gathered A stay L2-resident). 128x128 tile,
// BK=32, R5's proven 3-slot ring / lookahead-2 / 2-barrier schedule
// (R6's single-barrier variant measured -5%; R7's atomic epilogue -60%;
// both reverted). Swizzle kept from R6 (SQ_LDS_BANK_CONFLICT 3.47M -> 0).
// R8 parameter change: 8 waves per block (512 thr), per-wave output 64x32
// (acc 4x2). Same LDS (48KB -> 3 blocks/CU), same bytes and MFMA totals,
// but 24 waves/CU instead of 12: 2x the TLP against the vmcnt/barrier
// stall that dominates the per-iter period (~1300cy period vs ~230cy work,
// MfmaUtil 19%, nothing saturated).
// Per wave per iter: 2 DMAs (A 16 rows, B 16 rows), 6 ds_read_b128, 8 MFMA.
// vmcnt: 3 tiles x 2 loads in flight = 6; wait tile kt -> vmcnt(4).
// ---------------------------------------------------------------------------
__global__ __launch_bounds__(512) void moe_gemm(
    const u16* __restrict__ xb, const u16* __restrict__ wT,
    const int* __restrict__ cnt, const int* __restrict__ tokList,
    const float* __restrict__ eb, u16* __restrict__ ybuf) {
  int e  = blockIdx.x;
  int c  = cnt[e * 32];
  int m0 = blockIdx.z * 128;
  if (m0 >= c) return;
  int n0 = blockIdx.y * 128;
  __shared__ __align__(16) u16 As[3][128 * 32];
  __shared__ __align__(16) u16 Bs[3][128 * 32];
  __shared__ int tokS[128];
  int tid = threadIdx.x;
  if (tid < 128) {
    int gm = m0 + tid;
    tokS[tid] = (gm < c) ? tokList[e * SEG + gm] : tokList[e * SEG];
  }
  __syncthreads();
  int lane = tid & 63;
  int wv   = tid >> 6;            // 0..7
  // staging: wave wv covers rows [wv*16, wv*16+16) of A and of B.
  int rl  = lane >> 2;             // 0..15
  int kcp = lane & 3;              // physical chunk slot
  int kcd = kcp ^ ((rl >> 1) & 3); // data chunk fetched (8-row XOR swizzle)
  int rowL = wv * 16 + rl;
  const u16* gA0 = xb + (size_t)tokS[rowL] * 1024 + kcd * 8;
  const u16* wTe = wT + ((size_t)e << 20);
  const u16* gB0 = wTe + (size_t)(n0 + rowL) * 1024 + kcd * 8;
  int ldsO = (wv * 16) * 32;

  int wm = wv >> 2, wn = wv & 3;   // 2M x 4N wave grid; per-wave 64x32
  int lrow = lane & 15;
  int q    = lane >> 4;
  int sw   = (q ^ ((lrow >> 1) & 3)) * 8;   // matches 8-row write swizzle
  f32x4 acc[4][2];
#pragma unroll
  for (int i = 0; i < 4; ++i)
#pragma unroll
    for (int j = 0; j < 2; ++j) acc[i][j] = (f32x4){0.f, 0.f, 0.f, 0.f};

  // prologue: tiles 0,1 -> slots 0,1 (4 loads in flight per wave)
#pragma unroll
  for (int p = 0; p < 2; ++p) {
    int ko = p * 32;
    async_load16(gA0 + ko, As[p] + ldsO);
    async_load16(gB0 + ko, Bs[p] + ldsO);
  }

  int cur = 0;                       // slot of tile kt (kt % 3)
  for (int kt = 0; kt < 32; ++kt) {
    // A: all waves done READING slot (kt-1)%3 == slot (kt+2)%3 (iter kt-1's
    // compute consumed it; lgkmcnt-before-MFMA makes those reads complete).
    asm volatile("s_barrier" ::: "memory");
    if (kt < 30) {
      int st = cur - 1; if (st < 0) st += 3;   // (kt+2) % 3
      int ko = (kt + 2) * 32;
      async_load16(gA0 + ko, As[st] + ldsO);
      async_load16(gB0 + ko, Bs[st] + ldsO);
      // 6 outstanding (tiles kt,kt+1,kt+2); wait tile kt's 2 only
      asm volatile("s_waitcnt vmcnt(4)" ::: "memory");
    } else if (kt == 30) {
      asm volatile("s_waitcnt vmcnt(2)" ::: "memory");
    } else {
      asm volatile("s_waitcnt vmcnt(0)" ::: "memory");
    }
    // B: every wave's tile-kt DMA has landed in LDS
    asm volatile("s_barrier" ::: "memory");
    bf16x8 af[4], bfr[2];
#pragma unroll
    for (int mt = 0; mt < 4; ++mt)
      af[mt] = *(const bf16x8*)(As[cur] + (wm * 64 + mt * 16 + lrow) * 32 + sw);
#pragma unroll
    for (int nt = 0; nt < 2; ++nt)
      bfr[nt] = *(const bf16x8*)(Bs[cur] + (wn * 32 + nt * 16 + lrow) * 32 + sw);
#pragma unroll
    for (int mt = 0; mt < 4; ++mt)
#pragma unroll
      for (int nt = 0; nt < 2; ++nt)
        acc[mt][nt] = __builtin_amdgcn_mfma_f32_16x16x32_bf16(
            af[mt], bfr[nt], acc[mt][nt], 0, 0, 0);
    ++cur; if (cur == 3) cur = 0;
  }
  // epilogue: C/D layout col=lane&15, row=(lane>>4)*4+reg [m89]
  int rq = lane >> 4;
  float bias[2];
#pragma unroll
  for (int nt = 0; nt < 2; ++nt)
    bias[nt] = eb[e * 1024 + n0 + wn * 32 + nt * 16 + lrow];
  u16* yb = ybuf + ((size_t)(e * SEG + m0)) * 1024 + n0 + wn * 32 + lrow;
#pragma unroll
  for (int mt = 0; mt < 4; ++mt) {
#pragma unroll
    for (int r = 0; r < 4; ++r) {
      int ml = wm * 64 + mt * 16 + rq * 4 + r;
      u16* row = yb + (size_t)ml * 1024;
#pragma unroll
      for (int nt = 0; nt < 2; ++nt)
        row[nt * 16] = f32_to_bf16(acc[mt][nt][r] + bias[nt]);
    }
  }
}

// ---------------------------------------------------------------------------
// Kernel 3: combine. out[t] = w0*ybuf[idx0] + w1*ybuf[idx1]  (pure BW).
// ybuf reads stay cached (plain loads, L2/L3-resident); out is write-once
// -> nontemporal stores only here (R1 showed nt on ybuf was the harmful
// one: it pushed combine's reads to HBM).
// ---------------------------------------------------------------------------
__global__ __launch_bounds__(256) void combine_kernel(
    const u16* __restrict__ ybuf, const int* __restrict__ revIdx,
    const float* __restrict__ revW, float* __restrict__ out) {
  int tid = threadIdx.x, lane = tid & 63, wv = tid >> 6;
  for (int it = 0; it < 4; ++it) {
    int t  = blockIdx.x * 16 + wv * 4 + it;
    int i0 = revIdx[t * 2], i1 = revIdx[t * 2 + 1];
    float w0 = revW[t * 2], w1 = revW[t * 2 + 1];
    float o[16];
#pragma unroll
    for (int k = 0; k < 16; ++k) o[k] = 0.f;
    if (i0 >= 0) {
      const u16x8* y = (const u16x8*)(ybuf + (size_t)i0 * 1024);
#pragma unroll
      for (int jj = 0; jj < 2; ++jj) {
        u16x8 v = y[lane + 64 * jj];
#pragma unroll
        for (int k = 0; k < 8; ++k) o[jj * 8 + k] += w0 * bf16_to_f32(v[k]);
      }
    }
    if (i1 >= 0) {
      const u16x8* y = (const u16x8*)(ybuf + (size_t)i1 * 1024);
#pragma unroll
      for (int jj = 0; jj < 2; ++jj) {
        u16x8 v = y[lane + 64 * jj];
#pragma unroll
        for (int k = 0; k < 8; ++k) o[jj * 8 + k] += w1 * bf16_to_f32(v[k]);
      }
    }
    f32x4* o4 = (f32x4*)(out + (size_t)t * 1024);
#pragma unroll
    for (int jj = 0; jj < 2; ++jj)
#pragma unroll
      for (int h = 0; h < 2; ++h) {
        f32x4 vv = {o[jj * 8 + h * 4], o[jj * 8 + h * 4 + 1],
                    o[jj * 8 + h * 4 + 2], o[jj * 8 + h * 4 + 3]};
        __builtin_nontemporal_store(vv, &o4[2 * (lane + 64 * jj) + h]);
      }
  }
}

// ---------------------------------------------------------------------------
// Workspace layout (bytes), total ~64.2 MiB:
//   [0, 4096)        : int cnt[8*32] (one counter per 128B line)
//   [4096, +64K)     : tokList  8*2048 int (combined per-expert lists)
//   [+64K)           : revIdx   8192*2 int
//   [+64K)           : revW     8192*2 float
//   [+16M)           : xb   bf16 [8192][1024]
//   [+16M)           : wT   bf16 [8][1024][1024]
//   [+33.5M)         : ybuf bf16 [8*2048][1024]
// ---------------------------------------------------------------------------
extern "C" void kernel_launch(void* const* d_in, const int* in_sizes, int n_in,
                              void* d_out, int out_size, void* d_ws, size_t ws_size,
                              hipStream_t stream) {
  const float* x  = (const float*)d_in[0];
  const float* gw = (const float*)d_in[1];
  const float* gb = (const float*)d_in[2];
  const float* ew = (const float*)d_in[3];
  const float* eb = (const float*)d_in[4];
  float* out = (float*)d_out;
  char* ws = (char*)d_ws;
  int*   cnt     = (int*)ws;
  int*   tokList = (int*)(ws + 4096);
  int*   revIdx  = (int*)(ws + 4096 + 65536);
  float* revW    = (float*)(ws + 4096 + 131072);
  u16*   xb      = (u16*)(ws + 200704);
  u16*   wT      = (u16*)(ws + 200704 + 16777216);
  u16*   ybuf    = (u16*)(ws + 200704 + 33554432);

  hipMemsetAsync(cnt, 0, 4096, stream);
  prep_kernel<<<2560, 256, 0, stream>>>(x, gw, gb, ew, xb, wT, cnt, tokList,
                                        revIdx, revW);
  moe_gemm<<<dim3(8, 8, 16), 512, 0, stream>>>(xb, wT, cnt, tokList, eb, ybuf);
  combine_kernel<<<512, 256, 0, stream>>>(ybuf, revIdx, revW, out);
}

// Round 5
// 175.549 us; speedup vs baseline: 1.1825x; 1.0334x over previous
//
#include <hip/hip_runtime.h>
#include <hip/hip_bf16.h>
#include <stdint.h>

#define T_TOKENS 8192
#define D_DIM    1024
#define NE       10
#define NT       8
#define SEG      2048   // padded per-expert list capacity (actual ~1638+-40)

typedef unsigned short u16;
typedef __attribute__((ext_vector_type(8))) __bf16 bf16x8;
typedef __attribute__((ext_vector_type(4))) float  f32x4;
typedef __attribute__((ext_vector_type(8))) unsigned short u16x8;
typedef __attribute__((ext_vector_type(4))) unsigned short u16x4;

static __device__ __forceinline__ u16 f32_to_bf16(float f) {
  union { float f; uint32_t u; } v; v.f = f;
  uint32_t u = v.u;
  return (u16)((u + 0x7fffu + ((u >> 16) & 1u)) >> 16);
}
static __device__ __forceinline__ float bf16_to_f32(u16 u) {
  union { uint32_t u; float f; } v; v.u = ((uint32_t)u) << 16; return v.f;
}

// async 16B global->LDS DMA; LDS dest = wave-uniform base + lane*16 [m97/m104]
static __device__ __forceinline__ void async_load16(const u16* g, u16* l) {
  __builtin_amdgcn_global_load_lds(
      (const __attribute__((address_space(1))) void*)(const void*)g,
      (__attribute__((address_space(3))) void*)(void*)l, 16, 0, 0);
}

// ---------------------------------------------------------------------------
// Kernel 1: prep = gate + weight-transpose fused (independent, BW-bound).
//   blockIdx.x <  1024 : gate role (8 tokens/block; R9: was 16/block x 512
//                        blocks -> 1024 blocks for 2x TLP on the x-stream)
//   1024..3071         : transpose role (64x64 fp32->bf16 tile of W)
// Gate: fp32 logits -> softmax -> top-2 (strict > scan = lax.top_k
// lower-index tie-break) -> normalized true weights; bf16 x; combined
// per-expert token lists; reverse index+weight per (token,slot) for combine.
// ---------------------------------------------------------------------------
union PrepShared {
  struct { float gws[NE * D_DIM]; float gbs[NE]; int se[16]; float swt[16]; } g;
  struct { float tile[64][68]; } t;
};

__global__ __launch_bounds__(256) void prep_kernel(
    const float* __restrict__ x, const float* __restrict__ gw,
    const float* __restrict__ gb, const float* __restrict__ W,
    u16* __restrict__ xb, u16* __restrict__ wT,
    int* __restrict__ cnt, int* __restrict__ tokList,
    int* __restrict__ revIdx, float* __restrict__ revW) {
  __shared__ PrepShared sh;
  int tid = threadIdx.x;

  if (blockIdx.x >= 1024) {
    // ---- transpose role: W [e][d][j] fp32 -> wT [e][j][d] bf16 ----
    int tb = blockIdx.x - 1024;
    int e  = tb >> 8;
    int rem = tb & 255;
    int k0 = (rem >> 4) * 64;
    int n0 = (rem & 15) * 64;
    int cr = tid & 15;            // col-chunk (load) / k-chunk (store)
    int r0 = tid >> 4;            // 0..15
    const float* We = W + ((size_t)e << 20);
#pragma unroll
    for (int pass = 0; pass < 4; ++pass) {
      int r = pass * 16 + r0;     // k-row within tile
      f32x4 v = *(const f32x4*)&We[(size_t)(k0 + r) * 1024 + n0 + cr * 4];
#pragma unroll
      for (int j = 0; j < 4; ++j) sh.t.tile[cr * 4 + j][r] = v[j];
    }
    __syncthreads();
    u16* wTe = wT + ((size_t)e << 20);
#pragma unroll
    for (int pass = 0; pass < 4; ++pass) {
      int n = pass * 16 + r0;     // output row (n-dim)
      f32x4 tv = *(const f32x4*)&sh.t.tile[n][cr * 4];
      u16x4 pk;
#pragma unroll
      for (int j = 0; j < 4; ++j) pk[j] = f32_to_bf16(tv[j]);
      *(u16x4*)&wTe[(size_t)(n0 + n) * 1024 + k0 + cr * 4] = pk;
    }
    return;
  }

  // ---- gate role: 8 tokens/block ----
  {
    const f32x4* g4 = (const f32x4*)gw;
    f32x4* s4 = (f32x4*)sh.g.gws;
    for (int i = tid; i < NE * D_DIM / 4; i += 256) s4[i] = g4[i];
  }
  if (tid < NE) sh.g.gbs[tid] = gb[tid];
  __syncthreads();
  int lane = tid & 63;
  int wv   = tid >> 6;
  const f32x4* gws4 = (const f32x4*)sh.g.gws;
  for (int it = 0; it < 2; ++it) {
    int slot = wv * 2 + it;
    int t = blockIdx.x * 8 + slot;
    const f32x4* xr4 = (const f32x4*)(x + (size_t)t * D_DIM);
    f32x4 xv[4];
#pragma unroll
    for (int jj = 0; jj < 4; ++jj) xv[jj] = xr4[lane + 64 * jj];
    u16x4* xbr = (u16x4*)(xb + (size_t)t * D_DIM);
#pragma unroll
    for (int jj = 0; jj < 4; ++jj) {
      u16x4 pk;
#pragma unroll
      for (int k = 0; k < 4; ++k) pk[k] = f32_to_bf16(xv[jj][k]);
      xbr[lane + 64 * jj] = pk;
    }
    float logit[NE];
#pragma unroll
    for (int e = 0; e < NE; ++e) {
      float a = 0.f;
#pragma unroll
      for (int jj = 0; jj < 4; ++jj) {
        f32x4 gv = gws4[e * 256 + lane + 64 * jj];
#pragma unroll
        for (int k = 0; k < 4; ++k) a = fmaf(xv[jj][k], gv[k], a);
      }
#pragma unroll
      for (int off = 32; off >= 1; off >>= 1) a += __shfl_xor(a, off);
      logit[e] = a + sh.g.gbs[e];
    }
    float mx = logit[0];
#pragma unroll
    for (int e = 1; e < NE; ++e) mx = fmaxf(mx, logit[e]);
    float p[NE]; float s = 0.f;
#pragma unroll
    for (int e = 0; e < NE; ++e) { p[e] = expf(logit[e] - mx); s += p[e]; }
    int e0 = 0; float b0 = p[0];
#pragma unroll
    for (int e = 1; e < NE; ++e) if (p[e] > b0) { b0 = p[e]; e0 = e; }
    int e1 = -1; float b1 = -1.f;
#pragma unroll
    for (int e = 0; e < NE; ++e) if (e != e0 && p[e] > b1) { b1 = p[e]; e1 = e; }
    float w0 = b0 / s, w1 = b1 / s;
    float tw0 = (e0 < NT) ? w0 : 0.f;
    float tw1 = (e1 < NT) ? w1 : 0.f;
    float denom = tw0 + tw1;
    float nw0 = 0.f, nw1 = 0.f;
    if (denom > 0.f) { nw0 = tw0 / denom; nw1 = tw1 / denom; }
    if (lane == 0) {
      sh.g.se[slot * 2]     = (e0 < NT) ? e0 : -1;  sh.g.swt[slot * 2]     = nw0;
      sh.g.se[slot * 2 + 1] = (e1 < NT) ? e1 : -1;  sh.g.swt[slot * 2 + 1] = nw1;
      if (e0 >= NT) { revIdx[t * 2]     = -1; revW[t * 2]     = 0.f; }
      if (e1 >= NT) { revIdx[t * 2 + 1] = -1; revW[t * 2 + 1] = 0.f; }
    }
  }
  __syncthreads();
  // compaction: thread e<8 scans 16 (token,slot) entries; one padded atomic.
  if (tid < NT) {
    int e = tid, c = 0;
    for (int i = 0; i < 16; ++i) c += (sh.g.se[i] == e);
    if (c > 0) {
      int base = atomicAdd(&cnt[e * 32], c);
      int j = 0;
      for (int i = 0; i < 16; ++i) {
        if (sh.g.se[i] == e) {
          int tt  = blockIdx.x * 8 + (i >> 1);
          int pos = base + j;
          tokList[e * SEG + pos]   = tt;
          revIdx[tt * 2 + (i & 1)] = e * SEG + pos;
          revW[tt * 2 + (i & 1)]   = sh.g.swt[i];
          ++j;
        }
      }
    }
  }
}

// ---------------------------------------------------------------------------
// Kernel 2: per-expert gathered GEMM. grid x=expert (XCD-affine).
// R9: tile 256x128 (M x N), BK=32, 8 waves (2M x 4N, per-wave 128x32 out,
// acc 8x2). SAME proven sync skeleton as R5/R8 (3-slot ring, lookahead-2,
// issue-then-counted-vmcnt, 2 barriers/iter) — R8 showed doubling TLP
// (occupancy 19->38%) bought only -8%, so the per-ITERATION overhead
// (~70% of period, m233) is the cost; this doubles MFMA work amortized
// per barrier pair instead. Per iter per wave: 16 MFMA, 10 ds_read_b128,
// 3 DMAs (A rows 2x16, B rows 1x16). LDS 73KB -> 2 blocks/CU, 16 waves/CU.
// Grid (8,8,8)=512 blocks = exactly 2/CU, single residency pass, no tail.
// vmcnt: 3 tiles x 3 loads = 9 outstanding; wait tile kt -> vmcnt(6);
// drain 3/0 at kt=30/31. launch_bounds(512,4) pins VGPR<=128 (est ~95).
// Swizzle unchanged (8-row XOR, SQ_LDS_BANK_CONFLICT = 0).
// ---------------------------------------------------------------------------
__global__ __launch_bounds__(512, 4) void moe_gemm(
    const u16* __restrict__ xb, const u16* __restrict__ wT,
    const int* __restrict__ cnt, const int* __restrict__ tokList,
    const float* __restrict__ eb, u16* __restrict__ ybuf) {
  int e  = blockIdx.x;
  int c  = cnt[e * 32];
  int m0 = blockIdx.z * 256;
  if (m0 >= c) return;
  int n0 = blockIdx.y * 128;
  __shared__ __align__(16) u16 As[3][256 * 32];
  __shared__ __align__(16) u16 Bs[3][128 * 32];
  __shared__ int tokS[256];
  int tid = threadIdx.x;
  if (tid < 256) {
    int gm = m0 + tid;
    tokS[tid] = (gm < c) ? tokList[e * SEG + gm] : tokList[e * SEG];
  }
  __syncthreads();
  int lane = tid & 63;
  int wv   = tid >> 6;            // 0..7
  int rl  = lane >> 2;             // 0..15
  int kcp = lane & 3;              // physical chunk slot
  int kcd = kcp ^ ((rl >> 1) & 3); // data chunk fetched (8-row XOR swizzle)
  // staging: A rows [wv*32, wv*32+32) via two 16-row DMAs; B rows [wv*16,+16)
  int rowA0 = wv * 32 + rl, rowA1 = rowA0 + 16;
  int rowB  = wv * 16 + rl;
  const u16* gA0 = xb + (size_t)tokS[rowA0] * 1024 + kcd * 8;
  const u16* gA1 = xb + (size_t)tokS[rowA1] * 1024 + kcd * 8;
  const u16* wTe = wT + ((size_t)e << 20);
  const u16* gB0 = wTe + (size_t)(n0 + rowB) * 1024 + kcd * 8;
  int ldsA0 = (wv * 32) * 32, ldsA1 = ldsA0 + 16 * 32, ldsB0 = (wv * 16) * 32;

  int wm = wv >> 2, wn = wv & 3;   // 2M x 4N wave grid; per-wave 128x32
  int lrow = lane & 15;
  int q    = lane >> 4;
  int sw   = (q ^ ((lrow >> 1) & 3)) * 8;   // matches 8-row write swizzle
  f32x4 acc[8][2];
#pragma unroll
  for (int i = 0; i < 8; ++i)
#pragma unroll
    for (int j = 0; j < 2; ++j) acc[i][j] = (f32x4){0.f, 0.f, 0.f, 0.f};

  // prologue: tiles 0,1 -> slots 0,1 (6 loads in flight per wave)
#pragma unroll
  for (int p = 0; p < 2; ++p) {
    int ko = p * 32;
    async_load16(gA0 + ko, As[p] + ldsA0);
    async_load16(gA1 + ko, As[p] + ldsA1);
    async_load16(gB0 + ko, Bs[p] + ldsB0);
  }

  int cur = 0;                       // slot of tile kt (kt % 3)
  for (int kt = 0; kt < 32; ++kt) {
    // A: all waves done READING slot (kt-1)%3 == slot (kt+2)%3 (iter kt-1's
    // compute consumed it; lgkmcnt-before-MFMA makes those reads complete).
    asm volatile("s_barrier" ::: "memory");
    if (kt < 30) {
      int st = cur - 1; if (st < 0) st += 3;   // (kt+2) % 3
      int ko = (kt + 2) * 32;
      async_load16(gA0 + ko, As[st] + ldsA0);
      async_load16(gA1 + ko, As[st] + ldsA1);
      async_load16(gB0 + ko, Bs[st] + ldsB0);
      // 9 outstanding (tiles kt,kt+1,kt+2); wait tile kt's 3 only
      asm volatile("s_waitcnt vmcnt(6)" ::: "memory");
    } else if (kt == 30) {
      asm volatile("s_waitcnt vmcnt(3)" ::: "memory");
    } else {
      asm volatile("s_waitcnt vmcnt(0)" ::: "memory");
    }
    // B: every wave's tile-kt DMA has landed in LDS
    asm volatile("s_barrier" ::: "memory");
    bf16x8 bfr[2];
#pragma unroll
    for (int nt = 0; nt < 2; ++nt)
      bfr[nt] = *(const bf16x8*)(Bs[cur] + (wn * 32 + nt * 16 + lrow) * 32 + sw);
#pragma unroll
    for (int mt = 0; mt < 8; ++mt) {
      bf16x8 af = *(const bf16x8*)(As[cur] + (wm * 128 + mt * 16 + lrow) * 32 + sw);
#pragma unroll
      for (int nt = 0; nt < 2; ++nt)
        acc[mt][nt] = __builtin_amdgcn_mfma_f32_16x16x32_bf16(
            af, bfr[nt], acc[mt][nt], 0, 0, 0);
    }
    ++cur; if (cur == 3) cur = 0;
  }
  // epilogue: C/D layout col=lane&15, row=(lane>>4)*4+reg [m89]
  int rq = lane >> 4;
  float bias[2];
#pragma unroll
  for (int nt = 0; nt < 2; ++nt)
    bias[nt] = eb[e * 1024 + n0 + wn * 32 + nt * 16 + lrow];
  u16* yb = ybuf + ((size_t)(e * SEG + m0)) * 1024 + n0 + wn * 32 + lrow;
#pragma unroll
  for (int mt = 0; mt < 8; ++mt) {
#pragma unroll
    for (int r = 0; r < 4; ++r) {
      int ml = wm * 128 + mt * 16 + rq * 4 + r;
      u16* row = yb + (size_t)ml * 1024;
#pragma unroll
      for (int nt = 0; nt < 2; ++nt)
        row[nt * 16] = f32_to_bf16(acc[mt][nt][r] + bias[nt]);
    }
  }
}

// ---------------------------------------------------------------------------
// Kernel 3: combine. out[t] = w0*ybuf[idx0] + w1*ybuf[idx1]  (pure BW).
// R9: 2048 blocks x 4 tokens (was 512 x 16) — 4x TLP for the stream.
// ybuf reads stay cached (plain loads); out is write-once -> nt stores.
// ---------------------------------------------------------------------------
__global__ __launch_bounds__(256) void combine_kernel(
    const u16* __restrict__ ybuf, const int* __restrict__ revIdx,
    const float* __restrict__ revW, float* __restrict__ out) {
  int tid = threadIdx.x, lane = tid & 63, wv = tid >> 6;
  int t  = blockIdx.x * 4 + wv;
  int i0 = revIdx[t * 2], i1 = revIdx[t * 2 + 1];
  float w0 = revW[t * 2], w1 = revW[t * 2 + 1];
  float o[16];
#pragma unroll
  for (int k = 0; k < 16; ++k) o[k] = 0.f;
  if (i0 >= 0) {
    const u16x8* y = (const u16x8*)(ybuf + (size_t)i0 * 1024);
#pragma unroll
    for (int jj = 0; jj < 2; ++jj) {
      u16x8 v = y[lane + 64 * jj];
#pragma unroll
      for (int k = 0; k < 8; ++k) o[jj * 8 + k] += w0 * bf16_to_f32(v[k]);
    }
  }
  if (i1 >= 0) {
    const u16x8* y = (const u16x8*)(ybuf + (size_t)i1 * 1024);
#pragma unroll
    for (int jj = 0; jj < 2; ++jj) {
      u16x8 v = y[lane + 64 * jj];
#pragma unroll
      for (int k = 0; k < 8; ++k) o[jj * 8 + k] += w1 * bf16_to_f32(v[k]);
    }
  }
  f32x4* o4 = (f32x4*)(out + (size_t)t * 1024);
#pragma unroll
  for (int jj = 0; jj < 2; ++jj)
#pragma unroll
    for (int h = 0; h < 2; ++h) {
      f32x4 vv = {o[jj * 8 + h * 4], o[jj * 8 + h * 4 + 1],
                  o[jj * 8 + h * 4 + 2], o[jj * 8 + h * 4 + 3]};
      __builtin_nontemporal_store(vv, &o4[2 * (lane + 64 * jj) + h]);
    }
}

// ---------------------------------------------------------------------------
// Workspace layout (bytes), total ~64.2 MiB:
//   [0, 4096)        : int cnt[8*32] (one counter per 128B line)
//   [4096, +64K)     : tokList  8*2048 int (combined per-expert lists)
//   [+64K)           : revIdx   8192*2 int
//   [+64K)           : revW     8192*2 float
//   [+16M)           : xb   bf16 [8192][1024]
//   [+16M)           : wT   bf16 [8][1024][1024]
//   [+33.5M)         : ybuf bf16 [8*2048][1024]
// ---------------------------------------------------------------------------
extern "C" void kernel_launch(void* const* d_in, const int* in_sizes, int n_in,
                              void* d_out, int out_size, void* d_ws, size_t ws_size,
                              hipStream_t stream) {
  const float* x  = (const float*)d_in[0];
  const float* gw = (const float*)d_in[1];
  const float* gb = (const float*)d_in[2];
  const float* ew = (const float*)d_in[3];
  const float* eb = (const float*)d_in[4];
  float* out = (float*)d_out;
  char* ws = (char*)d_ws;
  int*   cnt     = (int*)ws;
  int*   tokList = (int*)(ws + 4096);
  int*   revIdx  = (int*)(ws + 4096 + 65536);
  float* revW    = (float*)(ws + 4096 + 131072);
  u16*   xb      = (u16*)(ws + 200704);
  u16*   wT      = (u16*)(ws + 200704 + 16777216);
  u16*   ybuf    = (u16*)(ws + 200704 + 33554432);

  hipMemsetAsync(cnt, 0, 4096, stream);
  prep_kernel<<<3072, 256, 0, stream>>>(x, gw, gb, ew, xb, wT, cnt, tokList,
                                        revIdx, revW);
  moe_gemm<<<dim3(8, 8, 8), 512, 0, stream>>>(xb, wT, cnt, tokList, eb, ybuf);
  combine_kernel<<<2048, 256, 0, stream>>>(ybuf, revIdx, revW, out);
}